// Round 4
// baseline (439.425 us; speedup 1.0000x reference)
//
#include <hip/hip_runtime.h>
#include <hip/hip_bf16.h>
#include <math.h>

typedef __hip_bfloat16 bf16;
typedef __attribute__((ext_vector_type(8))) short bf16x8;   // 8 x bf16 = 4 VGPRs
typedef __attribute__((ext_vector_type(4))) float f32x4;

#define D_MODEL 1024
#define N_HEADS 16
#define HEAD_D  64
#define SEQ     2048
#define BATCH   4
#define NROWS   (BATCH*SEQ)   // 8192

// softmax scale folded into Q at projection time: 1/sqrt(64) * log2(e)
#define SCALE_Q 0.18033688011112042f

#define MFMA(a,b,c) __builtin_amdgcn_mfma_f32_16x16x32_bf16(a,b,c,0,0,0)

#if __has_builtin(__builtin_amdgcn_exp2f)
#define EXP2(x) __builtin_amdgcn_exp2f(x)
#else
#define EXP2(x) exp2f(x)
#endif

// async global->LDS, 16B per lane. LDS dest = wave-uniform base + lane*16.
__device__ __forceinline__ void gload16(void* lds_uniform_base, const void* g) {
  __builtin_amdgcn_global_load_lds(
      (const __attribute__((address_space(1))) void*)g,
      (__attribute__((address_space(3))) void*)lds_uniform_base,
      16, 0, 0);
}

// fast packed f32->bf16 RNE: lo = a, hi = b  (bit-trick; used on cold paths)
__device__ __forceinline__ unsigned pkrne(float a, float b) {
  unsigned ua = __float_as_uint(a), ub = __float_as_uint(b);
  ua += 0x7FFFu + ((ua >> 16) & 1u);
  ub += 0x7FFFu + ((ub >> 16) & 1u);
  return (ua >> 16) | (ub & 0xFFFF0000u);
}
// hot-path packed f32->bf16 RNE: single gfx950 instruction (no builtin; asm)
__device__ __forceinline__ unsigned cvtpk(float a, float b) {
  unsigned r;
  asm("v_cvt_pk_bf16_f32 %0, %1, %2" : "=v"(r) : "v"(a), "v"(b));
  return r;
}
__device__ __forceinline__ bf16x8 cvt8rne(float4 a, float4 b) {
  union { bf16x8 v; unsigned u[4]; } u;
  u.u[0] = pkrne(a.x, a.y); u.u[1] = pkrne(a.z, a.w);
  u.u[2] = pkrne(b.x, b.y); u.u[3] = pkrne(b.z, b.w);
  return u.v;
}

// f32 -> bf16 bulk convert. grid*256*8 == element count.
__global__ __launch_bounds__(256)
void convw(const float* __restrict__ src, bf16* __restrict__ dst) {
  int idx = (blockIdx.x * 256 + threadIdx.x) * 8;
  float4 a = *(const float4*)(src + idx);
  float4 b = *(const float4*)(src + idx + 4);
  *(bf16x8*)(dst + idx) = cvt8rne(a, b);
}

// three 1024x1024 weights -> contiguous bf16 dst (1M elems apart). 1536 blocks.
__global__ __launch_bounds__(256)
void convw3(const float* __restrict__ s0, const float* __restrict__ s1,
            const float* __restrict__ s2, bf16* __restrict__ dst) {
  int g = blockIdx.x;
  const float* src = (g < 512) ? s0 : ((g < 1024) ? s1 : s2);
  int idx = ((g & 511) * 256 + threadIdx.x) * 8;
  float4 a = *(const float4*)(src + idx);
  float4 b = *(const float4*)(src + idx + 4);
  *(bf16x8*)(dst + (size_t)(g >> 9) * 1048576 + idx) = cvt8rne(a, b);
}

// -------------------------------------------------------------------------
// C(M'xN') = A(M'x1024) @ B(N'x1024)^T + bias, K=1024, all bf16 in.
// (Round-1 note: fusing f32->bf16 conversion into staging regressed +40us
//  per GEMM — it turned fire-and-forget global_load_lds DMA into a
//  synchronous load->cvt->ds_write chain. Reverted to pure bf16 staging.)
// MODE 0: out f32 row-major, bias[col]        (O-projection)
// MODE 1: out bf16 K-layout  [((b*16+h)*2048+m)*64+d], bias[col]
// MODE 2: flipped V: row=h*64+d, col=b*2048+m; out[(b*1024+row)*2048+m],
//         bias[row]
// MODE 3: RoPE Q scaled by SCALE_Q, out bf16 [((b*16+h)*2048+t)*64+d]
// block 256 (4 waves), tile 128x128, BK=64.
// LDS: 128 rows x 128B; 16B chunk c of row r stored at chunk c^(r&7).
// -------------------------------------------------------------------------
template<int MODE>
__global__ __launch_bounds__(256, 2)
void gemm_bt(const bf16* __restrict__ Xb, const bf16* __restrict__ Wb,
             const float* __restrict__ bias, void* __restrict__ outv,
             const int* __restrict__ pos) {
  __shared__ bf16 sA[128*64];
  __shared__ bf16 sB[128*64];

  const int tid  = threadIdx.x;
  const int lane = tid & 63, wid = tid >> 6;
  const int q4 = lane >> 4, l15 = lane & 15;
  const int rb = blockIdx.x * 128;
  const int cb = blockIdx.y * 128;
  const int wm = (wid >> 1) * 64, wn = (wid & 1) * 64;

  f32x4 acc[4][4];
  const f32x4 z4 = {0.f, 0.f, 0.f, 0.f};
#pragma unroll
  for (int i = 0; i < 4; ++i)
#pragma unroll
    for (int j = 0; j < 4; ++j) acc[i][j] = z4;

  for (int kt = 0; kt < 16; ++kt) {
    const int k0 = kt * 64;
#pragma unroll
    for (int i = 0; i < 4; ++i) {
      int o  = i*4096 + tid*16;
      int rr = o >> 7;
      int c0 = ((o >> 4) & 7) ^ (rr & 7);
      gload16((char*)sA + i*4096 + (wid << 10),
              Xb + (size_t)(rb + rr)*D_MODEL + k0 + c0*8);
      gload16((char*)sB + i*4096 + (wid << 10),
              Wb + (size_t)(cb + rr)*D_MODEL + k0 + c0*8);
    }
    __syncthreads();
#pragma unroll
    for (int kq = 0; kq < 2; ++kq) {
      bf16x8 af[4], bfr[4];
      const int cc = (kq*4 + q4) ^ (l15 & 7);
#pragma unroll
      for (int mi = 0; mi < 4; ++mi) {
        int r = wm + mi*16 + l15;
        af[mi] = *(const bf16x8*)((const char*)sA + r*128 + cc*16);
      }
#pragma unroll
      for (int ni = 0; ni < 4; ++ni) {
        int r = wn + ni*16 + l15;
        bfr[ni] = *(const bf16x8*)((const char*)sB + r*128 + cc*16);
      }
#pragma unroll
      for (int mi = 0; mi < 4; ++mi)
#pragma unroll
        for (int ni = 0; ni < 4; ++ni)
          acc[mi][ni] = MFMA(af[mi], bfr[ni], acc[mi][ni]);
    }
    __syncthreads();
  }

  // ---------------- epilogue ----------------
  if (MODE == 0) {
    float* outF = (float*)outv;
#pragma unroll
    for (int ni = 0; ni < 4; ++ni) {
      int col = cb + wn + ni*16 + l15;
      float bv = bias[col];
#pragma unroll
      for (int mi = 0; mi < 4; ++mi) {
        int row0 = rb + wm + mi*16 + q4*4;
#pragma unroll
        for (int r = 0; r < 4; ++r)
          outF[(size_t)(row0 + r)*D_MODEL + col] = acc[mi][ni][r] + bv;
      }
    }
  } else if (MODE == 1) {
    bf16* out = (bf16*)outv;
#pragma unroll
    for (int ni = 0; ni < 4; ++ni) {
      int col = cb + wn + ni*16 + l15;
      int h = col >> 6, d = col & 63;
      float bv = bias[col];
#pragma unroll
      for (int mi = 0; mi < 4; ++mi) {
#pragma unroll
        for (int r = 0; r < 4; ++r) {
          int row = rb + wm + mi*16 + q4*4 + r;
          int b = row >> 11, m = row & 2047;
          out[(size_t)((b*N_HEADS + h)*SEQ + m)*HEAD_D + d] =
              __float2bfloat16(acc[mi][ni][r] + bv);
        }
      }
    }
  } else if (MODE == 2) {  // flipped: row = h*64+d, col = b*2048+m
    bf16* out = (bf16*)outv;
#pragma unroll
    for (int mi = 0; mi < 4; ++mi) {
#pragma unroll
      for (int r = 0; r < 4; ++r) {
        int row = rb + wm + mi*16 + q4*4 + r;
        float bv = bias[row];
#pragma unroll
        for (int ni = 0; ni < 4; ++ni) {
          int col = cb + wn + ni*16 + l15;
          int b = col >> 11, m = col & 2047;
          out[(size_t)(b*D_MODEL + row)*SEQ + m] =
              __float2bfloat16(acc[mi][ni][r] + bv);
        }
      }
    }
  } else { // MODE 3: Q with RoPE, scaled by SCALE_Q
    bf16* out = (bf16*)outv;
    const bool is64 = (pos[NROWS - 1] == 0);
    const float CLOG = 13.287712379549449f / 32.0f;  // log2(10000)/32
    float invf0 = exp2f(-(float)(l15)      * CLOG);
    float invf1 = exp2f(-(float)(l15 + 16) * CLOG);
    int h = (cb + wn) >> 6;  // wave covers exactly one head (64 cols)
#pragma unroll
    for (int ni = 0; ni < 2; ++ni) {
      int col1 = cb + wn + ni*16 + l15;
      int d = ni*16 + l15;          // d in [0,32)
      float invf = (ni == 0) ? invf0 : invf1;
      float b1 = bias[col1];
      float b2 = bias[col1 + 32];
#pragma unroll
      for (int mi = 0; mi < 4; ++mi) {
#pragma unroll
        for (int r = 0; r < 4; ++r) {
          int row = rb + wm + mi*16 + q4*4 + r;
          int b = row >> 11, t = row & 2047;
          int pv = is64 ? pos[2*row] : pos[row];
          float ang = (float)pv * invf;
          float sn, cs;
          __sincosf(ang, &sn, &cs);
          float q1 = acc[mi][ni][r]   + b1;
          float q2 = acc[mi][ni+2][r] + b2;
          size_t base = (size_t)((b*N_HEADS + h)*SEQ + t)*HEAD_D;
          out[base + d]      = __float2bfloat16((q1*cs - q2*sn) * SCALE_Q);
          out[base + d + 32] = __float2bfloat16((q2*cs + q1*sn) * SCALE_Q);
        }
      }
    }
  }
}

// -------------------------------------------------------------------------
// Flash attention, S^T formulation + LDS-staged K/VT.
// grid = 1024 blocks 1D, XCD-swizzled: linear id n -> xcd-slot c=n&7,
// qt=(n>>3)&15, bh=c+8*(n>>7): all 16 q-tiles of one bh share n%8 -> same
// XCD L2 caches that bh's K/VT strips.
// block 256 (4 waves x 32 q-rows). Q pre-scaled by SCALE_Q (base-2 softmax).
// LDS (48KB): sK 16KB @0; sVT 16KB @16K; P: waves 0-1 alias sK (dead after
// QK barrier), waves 2-3 at [32K,48K). 3 barriers/iter.
// Round-4: T14 async-STAGE split — K/VT staged global->regs at iter top
// (latency hides under QK+softmax+PV), ds_write after the PV barrier.
// Byte placement in LDS identical to the old global_load_lds path
// (pre-swizzled global source + linear dest), so read side unchanged.
// __launch_bounds__(256,2) is MANDATORY: rounds 2 AND 5-of-prev-session
// both proved (256,3) spills (~50 regs over the 170 cap once AGPR
// accumulators are counted). (256,3) => WRITE_SIZE 16->270MB, 134->275us.
// -------------------------------------------------------------------------
__global__ __launch_bounds__(256, 2)
void attn_kernel(const bf16* __restrict__ Q, const bf16* __restrict__ K,
                 const bf16* __restrict__ VT, bf16* __restrict__ O) {
  __shared__ __align__(16) char smem[49152];
  char* sK  = smem;            // 128 rows x 128B, 16B chunks XOR-swizzled
  char* sVT = smem + 16384;    // 64 rows x 256B, 16B chunks XOR-swizzled

  const int tid  = threadIdx.x;
  const int lane = tid & 63, wid = tid >> 6;
  const int q4 = lane >> 4, l15 = lane & 15;
  const int n   = blockIdx.x;
  const int bh  = (n & 7) + 8 * (n >> 7);
  const int qb  = ((n >> 3) & 15) * 128;

  const bf16* Qp  = Q  + (size_t)bh * SEQ * HEAD_D;
  const bf16* Kp  = K  + (size_t)bh * SEQ * HEAD_D;
  const bf16* VTp = VT + (size_t)bh * HEAD_D * SEQ;
  // per-wave-private P^T: 32 rows(t) x 256B(m), swizzled. 8KB per wave.
  char* wP = smem + (wid & 1) * 8192 + (wid >> 1) * 32768;

  // resident Q fragments (B-operand): lane holds Q[t=l15(+16mi)][k=q4*8+j]
  bf16x8 qf[2][2];
#pragma unroll
  for (int mi = 0; mi < 2; ++mi)
#pragma unroll
    for (int kq = 0; kq < 2; ++kq) {
      int t = qb + wid*32 + mi*16 + l15;
      qf[mi][kq] = *(const bf16x8*)(Qp + (size_t)t*HEAD_D + kq*32 + q4*8);
    }

  const f32x4 z4 = {0.f, 0.f, 0.f, 0.f};
  f32x4 oacc[2][4];                 // O^T tiles: row=d (4q4+r), col=t (l15)
  float mrow[2], lrow[2];           // per-lane; t fixed per lane
#pragma unroll
  for (int mi = 0; mi < 2; ++mi) {
#pragma unroll
    for (int nd = 0; nd < 4; ++nd) oacc[mi][nd] = z4;
    mrow[mi] = -3.0e38f; lrow[mi] = 0.f;
  }

  // T14 staging registers: 4x16B K + 4x16B VT per thread (32 VGPRs)
  float4 kst[4], vst[4];
  auto load_tile = [&](int kv2) {
    const int m0n = kv2 * 128;
#pragma unroll
    for (int i = 0; i < 4; ++i) {
      int o  = i*4096 + tid*16;
      int rK = o >> 7;
      int cK = ((o >> 4) & 7) ^ (rK & 7);
      kst[i] = *(const float4*)(Kp + (size_t)(m0n + rK)*HEAD_D + cK*8);
      int rV = o >> 8;
      int cV = ((o >> 4) & 15) ^ (rV & 7);
      vst[i] = *(const float4*)(VTp + (size_t)rV*SEQ + m0n + cV*8);
    }
  };
  auto store_tile = [&]() {
#pragma unroll
    for (int i = 0; i < 4; ++i) {
      *(float4*)(sK  + i*4096 + tid*16) = kst[i];
      *(float4*)(sVT + i*4096 + tid*16) = vst[i];
    }
  };

  // prologue: stage tile 0 synchronously
  load_tile(0);
  store_tile();
  __syncthreads();

  for (int kv = 0; kv < 16; ++kv) {
    // issue next tile's global loads NOW; consumed by ds_write after PV.
    if (kv < 15) load_tile(kv + 1);

    // S^T = K·Q^T : st[mi][ni] row m = ni*16+4q4+r, col t = mi*16+l15
    f32x4 st[2][8];
#pragma unroll
    for (int mi = 0; mi < 2; ++mi)
#pragma unroll
      for (int ni = 0; ni < 8; ++ni) st[mi][ni] = z4;
    __builtin_amdgcn_s_setprio(1);
#pragma unroll
    for (int kq = 0; kq < 2; ++kq) {
      const int cc = (kq*4 + q4) ^ (l15 & 7);
#pragma unroll
      for (int ni = 0; ni < 8; ++ni) {
        bf16x8 kf = *(const bf16x8*)(sK + (ni*16 + l15)*128 + cc*16);
        st[0][ni] = MFMA(kf, qf[0][kq], st[0][ni]);
        st[1][ni] = MFMA(kf, qf[1][kq], st[1][ni]);
      }
    }
    __builtin_amdgcn_s_setprio(0);
    __syncthreads();   // all waves' sK reads done before P aliases it

    // online softmax over m; P^T -> wave-private LDS (no barrier needed)
#pragma unroll
    for (int mi = 0; mi < 2; ++mi) {
      // tree max (depth 5 instead of serial 32-chain)
      float tn[8];
#pragma unroll
      for (int ni = 0; ni < 8; ++ni)
        tn[ni] = fmaxf(fmaxf(st[mi][ni][0], st[mi][ni][1]),
                       fmaxf(st[mi][ni][2], st[mi][ni][3]));
      float t01 = fmaxf(tn[0], tn[1]), t23 = fmaxf(tn[2], tn[3]);
      float t45 = fmaxf(tn[4], tn[5]), t67 = fmaxf(tn[6], tn[7]);
      float mloc = fmaxf(fmaxf(t01, t23), fmaxf(t45, t67));
      mloc = fmaxf(mloc, __shfl_xor(mloc, 16, 64));
      mloc = fmaxf(mloc, __shfl_xor(mloc, 32, 64));
      float mn = fmaxf(mrow[mi], mloc);
      float al = EXP2(mrow[mi] - mn);
      mrow[mi] = mn;
      // 4 independent partial sums (depth 8+2 instead of serial 32-chain)
      float rs0 = 0.f, rs1 = 0.f, rs2 = 0.f, rs3 = 0.f;
#pragma unroll
      for (int ni = 0; ni < 8; ++ni) {
        float p0 = EXP2(st[mi][ni][0] - mn);
        float p1 = EXP2(st[mi][ni][1] - mn);
        float p2 = EXP2(st[mi][ni][2] - mn);
        float p3 = EXP2(st[mi][ni][3] - mn);
        st[mi][ni][0] = p0; st[mi][ni][1] = p1;
        st[mi][ni][2] = p2; st[mi][ni][3] = p3;
        rs0 += p0; rs1 += p1; rs2 += p2; rs3 += p3;
      }
      lrow[mi] = lrow[mi]*al + ((rs0 + rs1) + (rs2 + rs3));
#pragma unroll
      for (int nd = 0; nd < 4; ++nd)
#pragma unroll
        for (int r = 0; r < 4; ++r) oacc[mi][nd][r] *= al;
      // pack 4 consecutive-m p's (in-lane) -> one b64 write per ni.
      char* rowp = wP + (mi*16 + l15)*256;
#pragma unroll
      for (int ni = 0; ni < 8; ++ni) {
        uint2 pk;
        pk.x = cvtpk(st[mi][ni][0], st[mi][ni][1]);
        pk.y = cvtpk(st[mi][ni][2], st[mi][ni][3]);
        int c  = 2*ni + (q4 >> 1);
        int cs = c ^ (l15 & 7);
        *(uint2*)(rowp + cs*16 + 8*(q4 & 1)) = pk;
      }
    }

    // O^T += V^T · P^T  (A = V^T frag from sVT, B = P^T frag from own LDS)
    __builtin_amdgcn_s_setprio(1);
#pragma unroll
    for (int kk = 0; kk < 4; ++kk) {
      const int cc = (kk*4 + q4) ^ (l15 & 7);
      bf16x8 vf[4];
#pragma unroll
      for (int nd = 0; nd < 4; ++nd)
        vf[nd] = *(const bf16x8*)(sVT + (nd*16 + l15)*256 + cc*16);
#pragma unroll
      for (int mi = 0; mi < 2; ++mi) {
        bf16x8 pb = *(const bf16x8*)(wP + (mi*16 + l15)*256 + cc*16);
#pragma unroll
        for (int nd = 0; nd < 4; ++nd)
          oacc[mi][nd] = MFMA(vf[nd], pb, oacc[mi][nd]);
      }
    }
    __builtin_amdgcn_s_setprio(0);
    __syncthreads();   // PV+P reads done; LDS free for next tile's writes

    if (kv < 15) {
      store_tile();    // vmcnt wait is implicit on first reg use
      __syncthreads(); // staged data visible to all waves
    }
  }

  // epilogue: finish l across quads, O /= l, packed 8B stores
  const int b = bh >> 4, h = bh & 15;
#pragma unroll
  for (int mi = 0; mi < 2; ++mi) {
    float l = lrow[mi];
    l += __shfl_xor(l, 16, 64);
    l += __shfl_xor(l, 32, 64);
    float inv = 1.0f / l;
    int t = qb + wid*32 + mi*16 + l15;
#pragma unroll
    for (int nd = 0; nd < 4; ++nd) {
      uint2 pk;
      pk.x = pkrne(oacc[mi][nd][0]*inv, oacc[mi][nd][1]*inv);
      pk.y = pkrne(oacc[mi][nd][2]*inv, oacc[mi][nd][3]*inv);
      int d = nd*16 + 4*q4;
      *(uint2*)(O + (size_t)(b*SEQ + t)*D_MODEL + h*HEAD_D + d) = pk;
    }
  }
}

// -------------------------------------------------------------------------
extern "C" void kernel_launch(void* const* d_in, const int* in_sizes, int n_in,
                              void* d_out, int out_size, void* d_ws, size_t ws_size,
                              hipStream_t stream) {
  const float* query = (const float*)d_in[0];
  const float* key   = (const float*)d_in[1];
  const float* value = (const float*)d_in[2];
  const int*   pos   = (const int*)d_in[3];
  const float* Wq = (const float*)d_in[4];  const float* bq = (const float*)d_in[5];
  const float* Wk = (const float*)d_in[6];  const float* bk = (const float*)d_in[7];
  const float* Wv = (const float*)d_in[8];  const float* bv = (const float*)d_in[9];
  const float* Wo = (const float*)d_in[10]; const float* bo = (const float*)d_in[11];

  // ws layout (64 MB):
  //  [0,16M)  qbuf bf16 [b,h,t,d];  after attn: first 2MB = Wo bf16
  //  [16,32M) kbuf bf16 [b,h,m,d]
  //  [32,48M) vtbuf bf16 [b,h,d,m]
  //  [48,64M) obuf bf16 [b,t,h*64+d]; before attn: first 6MB = Wq/Wk/Wv bf16
  // d_out (32MB f32) doubles as bf16 activation scratch (16MB) until O-GEMM.
  char* ws = (char*)d_ws;
  bf16* qbuf  = (bf16*)(ws);
  bf16* kbuf  = (bf16*)(ws + (size_t)16777216);
  bf16* vtbuf = (bf16*)(ws + (size_t)33554432);
  bf16* obuf  = (bf16*)(ws + (size_t)50331648);
  bf16* wqb = obuf;                       // 1M bf16 = 2MB each, contiguous
  bf16* wkb = obuf + (size_t)1048576;
  bf16* wvb = obuf + (size_t)2097152;
  bf16* wob = qbuf;                       // written AFTER attn consumes qbuf
  bf16* xact = (bf16*)d_out;              // activation scratch in d_out

  dim3 blk(256);
  dim3 gproj(NROWS/128, D_MODEL/128);     // 64 x 8
  dim3 gprojT(D_MODEL/128, NROWS/128);    // 8 x 64 (flipped V)

  // Wq/Wk/Wv -> bf16 in one launch (2MB each, contiguous dst)
  convw3<<<1536, blk, 0, stream>>>(Wq, Wk, Wv, wqb);

  // V^T = (Wv X^T): A=wv bf16, B=value bf16 (converted into d_out scratch)
  convw<<<4096, blk, 0, stream>>>(value, xact);
  gemm_bt<2><<<gprojT, blk, 0, stream>>>(wvb, xact, bv, vtbuf, nullptr);

  convw<<<4096, blk, 0, stream>>>(key, xact);
  gemm_bt<1><<<gproj,  blk, 0, stream>>>(xact, wkb, bk, kbuf, nullptr);

  convw<<<4096, blk, 0, stream>>>(query, xact);
  gemm_bt<3><<<gproj,  blk, 0, stream>>>(xact, wqb, bq, qbuf, pos);

  attn_kernel<<<dim3(1024), blk, 0, stream>>>(qbuf, kbuf, vtbuf, obuf);

  // O-projection: A=obuf bf16, B=Wo bf16 (into qbuf, dead after attn), f32 out
  convw<<<512, blk, 0, stream>>>(Wo, wob);
  gemm_bt<0><<<gproj,  blk, 0, stream>>>(obuf, wob, bo, d_out, nullptr);
  (void)in_sizes; (void)n_in; (void)out_size; (void)ws_size;
}

// Round 6
// 382.185 us; speedup vs baseline: 1.1498x; 1.1498x over previous
//
#include <hip/hip_runtime.h>
#include <hip/hip_bf16.h>
#include <math.h>

typedef __hip_bfloat16 bf16;
typedef __attribute__((ext_vector_type(8))) short bf16x8;   // 8 x bf16 = 4 VGPRs
typedef __attribute__((ext_vector_type(4))) float f32x4;

#define D_MODEL 1024
#define N_HEADS 16
#define HEAD_D  64
#define SEQ     2048
#define BATCH   4
#define NROWS   (BATCH*SEQ)   // 8192

// softmax scale folded into Q at projection time: 1/sqrt(64) * log2(e)
#define SCALE_Q 0.18033688011112042f

#define MFMA(a,b,c) __builtin_amdgcn_mfma_f32_16x16x32_bf16(a,b,c,0,0,0)

#if __has_builtin(__builtin_amdgcn_exp2f)
#define EXP2(x) __builtin_amdgcn_exp2f(x)
#else
#define EXP2(x) exp2f(x)
#endif

// async global->LDS, 16B per lane. LDS dest = wave-uniform base + lane*16.
__device__ __forceinline__ void gload16(void* lds_uniform_base, const void* g) {
  __builtin_amdgcn_global_load_lds(
      (const __attribute__((address_space(1))) void*)g,
      (__attribute__((address_space(3))) void*)lds_uniform_base,
      16, 0, 0);
}

// fast packed f32->bf16 RNE: lo = a, hi = b  (bit-trick; used on cold paths)
__device__ __forceinline__ unsigned pkrne(float a, float b) {
  unsigned ua = __float_as_uint(a), ub = __float_as_uint(b);
  ua += 0x7FFFu + ((ua >> 16) & 1u);
  ub += 0x7FFFu + ((ub >> 16) & 1u);
  return (ua >> 16) | (ub & 0xFFFF0000u);
}
// hot-path packed f32->bf16 RNE: single gfx950 instruction (no builtin; asm)
__device__ __forceinline__ unsigned cvtpk(float a, float b) {
  unsigned r;
  asm("v_cvt_pk_bf16_f32 %0, %1, %2" : "=v"(r) : "v"(a), "v"(b));
  return r;
}
__device__ __forceinline__ bf16x8 cvt8rne(float4 a, float4 b) {
  union { bf16x8 v; unsigned u[4]; } u;
  u.u[0] = pkrne(a.x, a.y); u.u[1] = pkrne(a.z, a.w);
  u.u[2] = pkrne(b.x, b.y); u.u[3] = pkrne(b.z, b.w);
  return u.v;
}
// f32x4-pair -> bf16x8 via v_cvt_pk (hot path in GEMM f32-operand reads)
__device__ __forceinline__ bf16x8 cvt8pk(float4 a, float4 b) {
  union { bf16x8 v; unsigned u[4]; } u;
  u.u[0] = cvtpk(a.x, a.y); u.u[1] = cvtpk(a.z, a.w);
  u.u[2] = cvtpk(b.x, b.y); u.u[3] = cvtpk(b.z, b.w);
  return u.v;
}

// f32 -> bf16 bulk convert. grid*256*8 == element count.
__global__ __launch_bounds__(256)
void convw(const float* __restrict__ src, bf16* __restrict__ dst) {
  int idx = (blockIdx.x * 256 + threadIdx.x) * 8;
  float4 a = *(const float4*)(src + idx);
  float4 b = *(const float4*)(src + idx + 4);
  *(bf16x8*)(dst + idx) = cvt8rne(a, b);
}

// three 1024x1024 weights -> contiguous bf16 dst (1M elems apart). 1536 blocks.
__global__ __launch_bounds__(256)
void convw3(const float* __restrict__ s0, const float* __restrict__ s1,
            const float* __restrict__ s2, bf16* __restrict__ dst) {
  int g = blockIdx.x;
  const float* src = (g < 512) ? s0 : ((g < 1024) ? s1 : s2);
  int idx = ((g & 511) * 256 + threadIdx.x) * 8;
  float4 a = *(const float4*)(src + idx);
  float4 b = *(const float4*)(src + idx + 4);
  *(bf16x8*)(dst + (size_t)(g >> 9) * 1048576 + idx) = cvt8rne(a, b);
}

// -------------------------------------------------------------------------
// C(M'xN') = A(M'x1024) @ B(N'x1024)^T + bias, K=1024.
// AF32/BF32: that operand is f32 in global memory. It is staged into LDS
// AS F32 via the same async global_load_lds DMA (32KB tile, 256B rows,
// 16B chunk c of row r at slot c^(r&7)) and converted to bf16 on the READ
// side with v_cvt_pk_bf16_f32 (2x ds_read_b128 + 4 cvt_pk per fragment).
// This replaces the standalone convw pass over activations WITHOUT the
// round-0 mistake (reg-staging: sync load->cvt->ds_write chain, +40us).
// The DMA stays fire-and-forget; latency profile matches the bf16 path.
// MODE 0: out f32 row-major, bias[col]        (O-projection)
// MODE 1: out bf16 K-layout  [((b*16+h)*2048+m)*64+d], bias[col]
// MODE 2: flipped V: row=h*64+d, col=b*2048+m; out[(b*1024+row)*2048+m],
//         bias[row]
// MODE 3: RoPE Q scaled by SCALE_Q, out bf16 [((b*16+h)*2048+t)*64+d]
// block 256 (4 waves), tile 128x128, BK=64.
// bf16 LDS: 128 rows x 128B; 16B chunk c of row r stored at chunk c^(r&7).
// -------------------------------------------------------------------------
template<int MODE, int AF32, int BF32>
__global__ __launch_bounds__(256, 2)
void gemm_bt(const void* __restrict__ Xv, const void* __restrict__ Wv_,
             const float* __restrict__ bias, void* __restrict__ outv,
             const int* __restrict__ pos) {
  __shared__ __align__(16) char sA[AF32 ? 32768 : 16384];
  __shared__ __align__(16) char sB[BF32 ? 32768 : 16384];

  const int tid  = threadIdx.x;
  const int lane = tid & 63, wid = tid >> 6;
  const int q4 = lane >> 4, l15 = lane & 15;
  const int rb = blockIdx.x * 128;
  const int cb = blockIdx.y * 128;
  const int wm = (wid >> 1) * 64, wn = (wid & 1) * 64;

  f32x4 acc[4][4];
  const f32x4 z4 = {0.f, 0.f, 0.f, 0.f};
#pragma unroll
  for (int i = 0; i < 4; ++i)
#pragma unroll
    for (int j = 0; j < 4; ++j) acc[i][j] = z4;

  for (int kt = 0; kt < 16; ++kt) {
    const int k0 = kt * 64;
    // ---- stage A ----
    if (AF32) {
#pragma unroll
      for (int i = 0; i < 8; ++i) {
        int o  = i*4096 + tid*16;
        int rr = o >> 8;                      // 256B rows
        int c0 = ((o >> 4) & 15) ^ (rr & 7);
        gload16(sA + i*4096 + (wid << 10),
                (const float*)Xv + (size_t)(rb + rr)*D_MODEL + k0 + c0*4);
      }
    } else {
#pragma unroll
      for (int i = 0; i < 4; ++i) {
        int o  = i*4096 + tid*16;
        int rr = o >> 7;                      // 128B rows
        int c0 = ((o >> 4) & 7) ^ (rr & 7);
        gload16(sA + i*4096 + (wid << 10),
                (const bf16*)Xv + (size_t)(rb + rr)*D_MODEL + k0 + c0*8);
      }
    }
    // ---- stage B ----
    if (BF32) {
#pragma unroll
      for (int i = 0; i < 8; ++i) {
        int o  = i*4096 + tid*16;
        int rr = o >> 8;
        int c0 = ((o >> 4) & 15) ^ (rr & 7);
        gload16(sB + i*4096 + (wid << 10),
                (const float*)Wv_ + (size_t)(cb + rr)*D_MODEL + k0 + c0*4);
      }
    } else {
#pragma unroll
      for (int i = 0; i < 4; ++i) {
        int o  = i*4096 + tid*16;
        int rr = o >> 7;
        int c0 = ((o >> 4) & 7) ^ (rr & 7);
        gload16(sB + i*4096 + (wid << 10),
                (const bf16*)Wv_ + (size_t)(cb + rr)*D_MODEL + k0 + c0*8);
      }
    }
    __syncthreads();
#pragma unroll
    for (int kq = 0; kq < 2; ++kq) {
      bf16x8 af[4], bfr[4];
      const int cc  = (kq*4 + q4) ^ (l15 & 7);   // bf16: 8 chunks/row
      const int cf0 = kq*8 + q4*2;               // f32: 16 chunks/row
#pragma unroll
      for (int mi = 0; mi < 4; ++mi) {
        int r = wm + mi*16 + l15;
        if (AF32) {
          const char* rp = sA + r*256;
          float4 a0 = *(const float4*)(rp + ((cf0    ) ^ (l15 & 7))*16);
          float4 a1 = *(const float4*)(rp + ((cf0 + 1) ^ (l15 & 7))*16);
          af[mi] = cvt8pk(a0, a1);
        } else {
          af[mi] = *(const bf16x8*)(sA + r*128 + cc*16);
        }
      }
#pragma unroll
      for (int ni = 0; ni < 4; ++ni) {
        int r = wn + ni*16 + l15;
        if (BF32) {
          const char* rp = sB + r*256;
          float4 b0 = *(const float4*)(rp + ((cf0    ) ^ (l15 & 7))*16);
          float4 b1 = *(const float4*)(rp + ((cf0 + 1) ^ (l15 & 7))*16);
          bfr[ni] = cvt8pk(b0, b1);
        } else {
          bfr[ni] = *(const bf16x8*)(sB + r*128 + cc*16);
        }
      }
#pragma unroll
      for (int mi = 0; mi < 4; ++mi)
#pragma unroll
        for (int ni = 0; ni < 4; ++ni)
          acc[mi][ni] = MFMA(af[mi], bfr[ni], acc[mi][ni]);
    }
    __syncthreads();
  }

  // ---------------- epilogue ----------------
  if (MODE == 0) {
    float* outF = (float*)outv;
#pragma unroll
    for (int ni = 0; ni < 4; ++ni) {
      int col = cb + wn + ni*16 + l15;
      float bv = bias[col];
#pragma unroll
      for (int mi = 0; mi < 4; ++mi) {
        int row0 = rb + wm + mi*16 + q4*4;
#pragma unroll
        for (int r = 0; r < 4; ++r)
          outF[(size_t)(row0 + r)*D_MODEL + col] = acc[mi][ni][r] + bv;
      }
    }
  } else if (MODE == 1) {
    bf16* out = (bf16*)outv;
#pragma unroll
    for (int ni = 0; ni < 4; ++ni) {
      int col = cb + wn + ni*16 + l15;
      int h = col >> 6, d = col & 63;
      float bv = bias[col];
#pragma unroll
      for (int mi = 0; mi < 4; ++mi) {
#pragma unroll
        for (int r = 0; r < 4; ++r) {
          int row = rb + wm + mi*16 + q4*4 + r;
          int b = row >> 11, m = row & 2047;
          out[(size_t)((b*N_HEADS + h)*SEQ + m)*HEAD_D + d] =
              __float2bfloat16(acc[mi][ni][r] + bv);
        }
      }
    }
  } else if (MODE == 2) {  // flipped: row = h*64+d, col = b*2048+m
    bf16* out = (bf16*)outv;
#pragma unroll
    for (int mi = 0; mi < 4; ++mi) {
#pragma unroll
      for (int r = 0; r < 4; ++r) {
        int row = rb + wm + mi*16 + q4*4 + r;
        float bv = bias[row];
#pragma unroll
        for (int ni = 0; ni < 4; ++ni) {
          int col = cb + wn + ni*16 + l15;
          int b = col >> 11, m = col & 2047;
          out[(size_t)(b*D_MODEL + row)*SEQ + m] =
              __float2bfloat16(acc[mi][ni][r] + bv);
        }
      }
    }
  } else { // MODE 3: Q with RoPE, scaled by SCALE_Q
    bf16* out = (bf16*)outv;
    const bool is64 = (pos[NROWS - 1] == 0);
    const float CLOG = 13.287712379549449f / 32.0f;  // log2(10000)/32
    float invf0 = exp2f(-(float)(l15)      * CLOG);
    float invf1 = exp2f(-(float)(l15 + 16) * CLOG);
    int h = (cb + wn) >> 6;  // wave covers exactly one head (64 cols)
#pragma unroll
    for (int ni = 0; ni < 2; ++ni) {
      int col1 = cb + wn + ni*16 + l15;
      int d = ni*16 + l15;          // d in [0,32)
      float invf = (ni == 0) ? invf0 : invf1;
      float b1 = bias[col1];
      float b2 = bias[col1 + 32];
#pragma unroll
      for (int mi = 0; mi < 4; ++mi) {
#pragma unroll
        for (int r = 0; r < 4; ++r) {
          int row = rb + wm + mi*16 + q4*4 + r;
          int b = row >> 11, t = row & 2047;
          int pv = is64 ? pos[2*row] : pos[row];
          float ang = (float)pv * invf;
          float sn, cs;
          __sincosf(ang, &sn, &cs);
          float q1 = acc[mi][ni][r]   + b1;
          float q2 = acc[mi][ni+2][r] + b2;
          size_t base = (size_t)((b*N_HEADS + h)*SEQ + t)*HEAD_D;
          out[base + d]      = __float2bfloat16((q1*cs - q2*sn) * SCALE_Q);
          out[base + d + 32] = __float2bfloat16((q2*cs + q1*sn) * SCALE_Q);
        }
      }
    }
  }
}

// -------------------------------------------------------------------------
// Flash attention, S^T formulation + LDS-staged K/VT. (round-3 exact, the
// verified 125.5us version.)
// grid = 1024 blocks 1D, XCD-swizzled. block 256 (4 waves x 32 q-rows).
// Q pre-scaled by SCALE_Q (base-2 softmax).
// LDS (48KB): sK 16KB @0; sVT 16KB @16K; P: waves 0-1 alias sK (dead after
// QK barrier), waves 2-3 at [32K,48K). 3 barriers/iter.
// __launch_bounds__(256,2) is MANDATORY: (256,3) spills (round 2).
// NO live-register staging across the MFMA regions: round 4 proved even
// +32 VGPRs (T14 reg-staging) re-triggers the spill (WRITE 16->246MB,
// 125->202us). Pipelining here must be LDS/DMA-side, zero registers.
// -------------------------------------------------------------------------
__global__ __launch_bounds__(256, 2)
void attn_kernel(const bf16* __restrict__ Q, const bf16* __restrict__ K,
                 const bf16* __restrict__ VT, bf16* __restrict__ O) {
  __shared__ __align__(16) char smem[49152];
  char* sK  = smem;            // 128 rows x 128B, 16B chunks XOR-swizzled
  char* sVT = smem + 16384;    // 64 rows x 256B, 16B chunks XOR-swizzled

  const int tid  = threadIdx.x;
  const int lane = tid & 63, wid = tid >> 6;
  const int q4 = lane >> 4, l15 = lane & 15;
  const int n   = blockIdx.x;
  const int bh  = (n & 7) + 8 * (n >> 7);
  const int qb  = ((n >> 3) & 15) * 128;

  const bf16* Qp  = Q  + (size_t)bh * SEQ * HEAD_D;
  const bf16* Kp  = K  + (size_t)bh * SEQ * HEAD_D;
  const bf16* VTp = VT + (size_t)bh * HEAD_D * SEQ;
  // per-wave-private P^T: 32 rows(t) x 256B(m), swizzled. 8KB per wave.
  char* wP = smem + (wid & 1) * 8192 + (wid >> 1) * 32768;

  // resident Q fragments (B-operand): lane holds Q[t=l15(+16mi)][k=q4*8+j]
  bf16x8 qf[2][2];
#pragma unroll
  for (int mi = 0; mi < 2; ++mi)
#pragma unroll
    for (int kq = 0; kq < 2; ++kq) {
      int t = qb + wid*32 + mi*16 + l15;
      qf[mi][kq] = *(const bf16x8*)(Qp + (size_t)t*HEAD_D + kq*32 + q4*8);
    }

  const f32x4 z4 = {0.f, 0.f, 0.f, 0.f};
  f32x4 oacc[2][4];                 // O^T tiles: row=d (4q4+r), col=t (l15)
  float mrow[2], lrow[2];           // per-lane; t fixed per lane
#pragma unroll
  for (int mi = 0; mi < 2; ++mi) {
#pragma unroll
    for (int nd = 0; nd < 4; ++nd) oacc[mi][nd] = z4;
    mrow[mi] = -3.0e38f; lrow[mi] = 0.f;
  }

  for (int kv = 0; kv < 16; ++kv) {
    const int m0 = kv * 128;
    // stage K tile (128x64 elems): async, swizzled
#pragma unroll
    for (int i = 0; i < 4; ++i) {
      int o  = i*4096 + tid*16;
      int rr = o >> 7;
      int c0 = ((o >> 4) & 7) ^ (rr & 7);
      gload16(sK + i*4096 + (wid << 10),
              Kp + (size_t)(m0 + rr)*HEAD_D + c0*8);
    }
    // stage VT tile (64x128 elems): async, swizzled
#pragma unroll
    for (int i = 0; i < 4; ++i) {
      int o  = i*4096 + tid*16;
      int rr = o >> 8;
      int c0 = ((o >> 4) & 15) ^ (rr & 7);
      gload16(sVT + i*4096 + (wid << 10),
              VTp + (size_t)rr*SEQ + m0 + c0*8);
    }
    __syncthreads();   // staging complete

    // S^T = K·Q^T : st[mi][ni] row m = ni*16+4q4+r, col t = mi*16+l15
    f32x4 st[2][8];
#pragma unroll
    for (int mi = 0; mi < 2; ++mi)
#pragma unroll
      for (int ni = 0; ni < 8; ++ni) st[mi][ni] = z4;
#pragma unroll
    for (int kq = 0; kq < 2; ++kq) {
      const int cc = (kq*4 + q4) ^ (l15 & 7);
#pragma unroll
      for (int ni = 0; ni < 8; ++ni) {
        bf16x8 kf = *(const bf16x8*)(sK + (ni*16 + l15)*128 + cc*16);
        st[0][ni] = MFMA(kf, qf[0][kq], st[0][ni]);
        st[1][ni] = MFMA(kf, qf[1][kq], st[1][ni]);
      }
    }
    __syncthreads();   // all waves' sK reads done before P aliases it

    // online softmax over m; P^T -> wave-private LDS (no barrier needed)
#pragma unroll
    for (int mi = 0; mi < 2; ++mi) {
      float mloc = st[mi][0][0];
#pragma unroll
      for (int ni = 0; ni < 8; ++ni)
#pragma unroll
        for (int r = 0; r < 4; ++r) mloc = fmaxf(mloc, st[mi][ni][r]);
      mloc = fmaxf(mloc, __shfl_xor(mloc, 16, 64));
      mloc = fmaxf(mloc, __shfl_xor(mloc, 32, 64));
      float mn = fmaxf(mrow[mi], mloc);
      float al = EXP2(mrow[mi] - mn);
      mrow[mi] = mn;
      float rs = 0.f;
#pragma unroll
      for (int ni = 0; ni < 8; ++ni)
#pragma unroll
        for (int r = 0; r < 4; ++r) {
          float p = EXP2(st[mi][ni][r] - mn);
          st[mi][ni][r] = p;
          rs += p;
        }
      lrow[mi] = lrow[mi]*al + rs;
#pragma unroll
      for (int nd = 0; nd < 4; ++nd)
#pragma unroll
        for (int r = 0; r < 4; ++r) oacc[mi][nd][r] *= al;
      // pack 4 consecutive-m p's (in-lane) -> one b64 write per ni.
      // v_cvt_pk_bf16_f32: 1 instr/pair vs pkrne's 5.
      char* rowp = wP + (mi*16 + l15)*256;
#pragma unroll
      for (int ni = 0; ni < 8; ++ni) {
        uint2 pk;
        pk.x = cvtpk(st[mi][ni][0], st[mi][ni][1]);
        pk.y = cvtpk(st[mi][ni][2], st[mi][ni][3]);
        int c  = 2*ni + (q4 >> 1);
        int cs = c ^ (l15 & 7);
        *(uint2*)(rowp + cs*16 + 8*(q4 & 1)) = pk;
      }
    }

    // O^T += V^T · P^T  (A = V^T frag from sVT, B = P^T frag from own LDS)
#pragma unroll
    for (int kk = 0; kk < 4; ++kk) {
      const int cc = (kk*4 + q4) ^ (l15 & 7);
      bf16x8 vf[4];
#pragma unroll
      for (int nd = 0; nd < 4; ++nd)
        vf[nd] = *(const bf16x8*)(sVT + (nd*16 + l15)*256 + cc*16);
#pragma unroll
      for (int mi = 0; mi < 2; ++mi) {
        bf16x8 pb = *(const bf16x8*)(wP + (mi*16 + l15)*256 + cc*16);
#pragma unroll
        for (int nd = 0; nd < 4; ++nd)
          oacc[mi][nd] = MFMA(vf[nd], pb, oacc[mi][nd]);
      }
    }
    __syncthreads();   // PV reads done before next-iter staging overwrites
  }

  // epilogue: finish l across quads, O /= l, packed 8B stores
  const int b = bh >> 4, h = bh & 15;
#pragma unroll
  for (int mi = 0; mi < 2; ++mi) {
    float l = lrow[mi];
    l += __shfl_xor(l, 16, 64);
    l += __shfl_xor(l, 32, 64);
    float inv = 1.0f / l;
    int t = qb + wid*32 + mi*16 + l15;
#pragma unroll
    for (int nd = 0; nd < 4; ++nd) {
      uint2 pk;
      pk.x = pkrne(oacc[mi][nd][0]*inv, oacc[mi][nd][1]*inv);
      pk.y = pkrne(oacc[mi][nd][2]*inv, oacc[mi][nd][3]*inv);
      int d = nd*16 + 4*q4;
      *(uint2*)(O + (size_t)(b*SEQ + t)*D_MODEL + h*HEAD_D + d) = pk;
    }
  }
}

// -------------------------------------------------------------------------
extern "C" void kernel_launch(void* const* d_in, const int* in_sizes, int n_in,
                              void* d_out, int out_size, void* d_ws, size_t ws_size,
                              hipStream_t stream) {
  const float* query = (const float*)d_in[0];
  const float* key   = (const float*)d_in[1];
  const float* value = (const float*)d_in[2];
  const int*   pos   = (const int*)d_in[3];
  const float* Wq = (const float*)d_in[4];  const float* bq = (const float*)d_in[5];
  const float* Wk = (const float*)d_in[6];  const float* bk = (const float*)d_in[7];
  const float* Wv = (const float*)d_in[8];  const float* bv = (const float*)d_in[9];
  const float* Wo = (const float*)d_in[10]; const float* bo = (const float*)d_in[11];

  // ws layout (64 MB):
  //  [0,16M)  qbuf bf16 [b,h,t,d];  after attn: first 2MB = Wo bf16
  //  [16,32M) kbuf bf16 [b,h,m,d]
  //  [32,48M) vtbuf bf16 [b,h,d,m]
  //  [48,64M) obuf bf16 [b,t,h*64+d]; before attn: first 6MB = Wq/Wk/Wv bf16
  // Activations (query/key/value) are consumed as f32 directly by the
  // projection GEMMs (DMA-f32 staging + read-side cvt_pk) — no conv pass.
  char* ws = (char*)d_ws;
  bf16* qbuf  = (bf16*)(ws);
  bf16* kbuf  = (bf16*)(ws + (size_t)16777216);
  bf16* vtbuf = (bf16*)(ws + (size_t)33554432);
  bf16* obuf  = (bf16*)(ws + (size_t)50331648);
  bf16* wqb = obuf;                       // 1M bf16 = 2MB each, contiguous
  bf16* wkb = obuf + (size_t)1048576;
  bf16* wvb = obuf + (size_t)2097152;
  bf16* wob = qbuf;                       // written AFTER attn consumes qbuf

  dim3 blk(256);
  dim3 gproj(NROWS/128, D_MODEL/128);     // 64 x 8
  dim3 gprojT(D_MODEL/128, NROWS/128);    // 8 x 64 (flipped V)

  // Wq/Wk/Wv -> bf16 in one launch (2MB each, contiguous dst)
  convw3<<<1536, blk, 0, stream>>>(Wq, Wk, Wv, wqb);

  // V^T = (Wv X^T): A=wv bf16 (DMA), B=value f32 (DMA-f32 + read-side cvt)
  gemm_bt<2,0,1><<<gprojT, blk, 0, stream>>>(wvb, value, bv, vtbuf, nullptr);

  // K: A=key f32 (DMA-f32), B=wk bf16
  gemm_bt<1,1,0><<<gproj,  blk, 0, stream>>>(key, wkb, bk, kbuf, nullptr);

  // Q + RoPE: A=query f32 (DMA-f32), B=wq bf16
  gemm_bt<3,1,0><<<gproj,  blk, 0, stream>>>(query, wqb, bq, qbuf, pos);

  attn_kernel<<<dim3(1024), blk, 0, stream>>>(qbuf, kbuf, vtbuf, obuf);

  // O-projection: A=obuf bf16, B=Wo bf16 (into qbuf, dead after attn), f32 out
  convw<<<512, blk, 0, stream>>>(Wo, wob);
  gemm_bt<0,0,0><<<gproj,  blk, 0, stream>>>(obuf, wob, bo, d_out, nullptr);
  (void)in_sizes; (void)n_in; (void)out_size; (void)ws_size;
}

// Round 14
// 368.532 us; speedup vs baseline: 1.1924x; 1.0370x over previous
//
#include <hip/hip_runtime.h>
#include <hip/hip_bf16.h>
#include <math.h>

typedef __hip_bfloat16 bf16;
typedef __attribute__((ext_vector_type(8))) short bf16x8;   // 8 x bf16 = 4 VGPRs
typedef __attribute__((ext_vector_type(4))) float f32x4;

#define D_MODEL 1024
#define N_HEADS 16
#define HEAD_D  64
#define SEQ     2048
#define BATCH   4
#define NROWS   (BATCH*SEQ)   // 8192

// softmax scale folded into Q at projection time: 1/sqrt(64) * log2(e)
#define SCALE_Q 0.18033688011112042f

#define MFMA(a,b,c) __builtin_amdgcn_mfma_f32_16x16x32_bf16(a,b,c,0,0,0)

#if __has_builtin(__builtin_amdgcn_exp2f)
#define EXP2(x) __builtin_amdgcn_exp2f(x)
#else
#define EXP2(x) exp2f(x)
#endif

// async global->LDS, 16B per lane. LDS dest = wave-uniform base + lane*16.
__device__ __forceinline__ void gload16(void* lds_uniform_base, const void* g) {
  __builtin_amdgcn_global_load_lds(
      (const __attribute__((address_space(1))) void*)g,
      (__attribute__((address_space(3))) void*)lds_uniform_base,
      16, 0, 0);
}

// fast packed f32->bf16 RNE: lo = a, hi = b  (bit-trick; used on cold paths)
__device__ __forceinline__ unsigned pkrne(float a, float b) {
  unsigned ua = __float_as_uint(a), ub = __float_as_uint(b);
  ua += 0x7FFFu + ((ua >> 16) & 1u);
  ub += 0x7FFFu + ((ub >> 16) & 1u);
  return (ua >> 16) | (ub & 0xFFFF0000u);
}
// hot-path packed f32->bf16 RNE: single gfx950 instruction (no builtin; asm)
__device__ __forceinline__ unsigned cvtpk(float a, float b) {
  unsigned r;
  asm("v_cvt_pk_bf16_f32 %0, %1, %2" : "=v"(r) : "v"(a), "v"(b));
  return r;
}
__device__ __forceinline__ bf16x8 cvt8rne(float4 a, float4 b) {
  union { bf16x8 v; unsigned u[4]; } u;
  u.u[0] = pkrne(a.x, a.y); u.u[1] = pkrne(a.z, a.w);
  u.u[2] = pkrne(b.x, b.y); u.u[3] = pkrne(b.z, b.w);
  return u.v;
}

// f32 -> bf16 bulk convert. grid*256*8 == element count.
__global__ __launch_bounds__(256)
void convw(const float* __restrict__ src, bf16* __restrict__ dst) {
  int idx = (blockIdx.x * 256 + threadIdx.x) * 8;
  float4 a = *(const float4*)(src + idx);
  float4 b = *(const float4*)(src + idx + 4);
  *(bf16x8*)(dst + idx) = cvt8rne(a, b);
}

// three 1024x1024 weights -> contiguous bf16 dst (1M elems apart). 1536 blocks.
__global__ __launch_bounds__(256)
void convw3(const float* __restrict__ s0, const float* __restrict__ s1,
            const float* __restrict__ s2, bf16* __restrict__ dst) {
  int g = blockIdx.x;
  const float* src = (g < 512) ? s0 : ((g < 1024) ? s1 : s2);
  int idx = ((g & 511) * 256 + threadIdx.x) * 8;
  float4 a = *(const float4*)(src + idx);
  float4 b = *(const float4*)(src + idx + 4);
  *(bf16x8*)(dst + (size_t)(g >> 9) * 1048576 + idx) = cvt8rne(a, b);
}

// -------------------------------------------------------------------------
// C(M'xN') = A(M'x1024) @ B(N'x1024)^T + bias, K=1024, all bf16 in.
// Round-6 notes: (a) fusing f32->bf16 conversion into staging regressed
//  both ways tried (round-0 reg-staging +40us/GEMM; round-6 DMA-f32
//  +18us/GEMM — doubling staged bytes lengthens the serialized vmcnt(0)
//  drain at the barrier; conv passes move those bytes at streaming BW
//  instead). Activations stay pre-converted by convw.
// Round-7: T3 minimum 2-phase pipeline — double-buffered LDS (64KB),
//  next tile's global_load_lds issued BEFORE current tile's ds_read+MFMA,
//  ONE __syncthreads per K-step (its implicit vmcnt(0) drain lands after
//  the whole compute phase has covered the load latency). Old structure
//  exposed full staging latency every K-step (2 barriers).
// MODE 0: out f32 row-major, bias[col]        (O-projection)
// MODE 1: out bf16 K-layout  [((b*16+h)*2048+m)*64+d], bias[col]
// MODE 2: flipped V: row=h*64+d, col=b*2048+m; out[(b*1024+row)*2048+m],
//         bias[row]
// MODE 3: RoPE Q scaled by SCALE_Q, out bf16 [((b*16+h)*2048+t)*64+d]
// block 256 (4 waves), tile 128x128, BK=64.
// LDS: per buffer 128 rows x 128B; 16B chunk c of row r at chunk c^(r&7).
// -------------------------------------------------------------------------
template<int MODE>
__global__ __launch_bounds__(256, 2)
void gemm_bt(const bf16* __restrict__ Xb, const bf16* __restrict__ Wb,
             const float* __restrict__ bias, void* __restrict__ outv,
             const int* __restrict__ pos) {
  __shared__ bf16 sA[2][128*64];
  __shared__ bf16 sB[2][128*64];

  const int tid  = threadIdx.x;
  const int lane = tid & 63, wid = tid >> 6;
  const int q4 = lane >> 4, l15 = lane & 15;
  const int rb = blockIdx.x * 128;
  const int cb = blockIdx.y * 128;
  const int wm = (wid >> 1) * 64, wn = (wid & 1) * 64;

  f32x4 acc[4][4];
  const f32x4 z4 = {0.f, 0.f, 0.f, 0.f};
#pragma unroll
  for (int i = 0; i < 4; ++i)
#pragma unroll
    for (int j = 0; j < 4; ++j) acc[i][j] = z4;

  auto stage = [&](int kt, int buf) {
    const int k0 = kt * 64;
#pragma unroll
    for (int i = 0; i < 4; ++i) {
      int o  = i*4096 + tid*16;
      int rr = o >> 7;
      int c0 = ((o >> 4) & 7) ^ (rr & 7);
      gload16((char*)sA[buf] + i*4096 + (wid << 10),
              Xb + (size_t)(rb + rr)*D_MODEL + k0 + c0*8);
      gload16((char*)sB[buf] + i*4096 + (wid << 10),
              Wb + (size_t)(cb + rr)*D_MODEL + k0 + c0*8);
    }
  };

  // prologue: stage tile 0, drain, enter loop
  stage(0, 0);
  __syncthreads();

  int cur = 0;
  for (int kt = 0; kt < 16; ++kt) {
    // issue next tile's DMA first: latency hides under this tile's compute
    if (kt < 15) stage(kt + 1, cur ^ 1);
    const char* pA = (const char*)sA[cur];
    const char* pB = (const char*)sB[cur];
#pragma unroll
    for (int kq = 0; kq < 2; ++kq) {
      bf16x8 af[4], bfr[4];
      const int cc = (kq*4 + q4) ^ (l15 & 7);
#pragma unroll
      for (int mi = 0; mi < 4; ++mi) {
        int r = wm + mi*16 + l15;
        af[mi] = *(const bf16x8*)(pA + r*128 + cc*16);
      }
#pragma unroll
      for (int ni = 0; ni < 4; ++ni) {
        int r = wn + ni*16 + l15;
        bfr[ni] = *(const bf16x8*)(pB + r*128 + cc*16);
      }
#pragma unroll
      for (int mi = 0; mi < 4; ++mi)
#pragma unroll
        for (int ni = 0; ni < 4; ++ni)
          acc[mi][ni] = MFMA(af[mi], bfr[ni], acc[mi][ni]);
    }
    // one barrier per K-step: implicit vmcnt(0) confirms next tile staged,
    // and all waves are done reading buf[cur] before it's restaged.
    __syncthreads();
    cur ^= 1;
  }

  // ---------------- epilogue ----------------
  if (MODE == 0) {
    float* outF = (float*)outv;
#pragma unroll
    for (int ni = 0; ni < 4; ++ni) {
      int col = cb + wn + ni*16 + l15;
      float bv = bias[col];
#pragma unroll
      for (int mi = 0; mi < 4; ++mi) {
        int row0 = rb + wm + mi*16 + q4*4;
#pragma unroll
        for (int r = 0; r < 4; ++r)
          outF[(size_t)(row0 + r)*D_MODEL + col] = acc[mi][ni][r] + bv;
      }
    }
  } else if (MODE == 1) {
    bf16* out = (bf16*)outv;
#pragma unroll
    for (int ni = 0; ni < 4; ++ni) {
      int col = cb + wn + ni*16 + l15;
      int h = col >> 6, d = col & 63;
      float bv = bias[col];
#pragma unroll
      for (int mi = 0; mi < 4; ++mi) {
#pragma unroll
        for (int r = 0; r < 4; ++r) {
          int row = rb + wm + mi*16 + q4*4 + r;
          int b = row >> 11, m = row & 2047;
          out[(size_t)((b*N_HEADS + h)*SEQ + m)*HEAD_D + d] =
              __float2bfloat16(acc[mi][ni][r] + bv);
        }
      }
    }
  } else if (MODE == 2) {  // flipped: row = h*64+d, col = b*2048+m
    bf16* out = (bf16*)outv;
#pragma unroll
    for (int mi = 0; mi < 4; ++mi) {
#pragma unroll
      for (int r = 0; r < 4; ++r) {
        int row = rb + wm + mi*16 + q4*4 + r;
        float bv = bias[row];
#pragma unroll
        for (int ni = 0; ni < 4; ++ni) {
          int col = cb + wn + ni*16 + l15;
          int b = col >> 11, m = col & 2047;
          out[(size_t)(b*D_MODEL + row)*SEQ + m] =
              __float2bfloat16(acc[mi][ni][r] + bv);
        }
      }
    }
  } else { // MODE 3: Q with RoPE, scaled by SCALE_Q
    bf16* out = (bf16*)outv;
    const bool is64 = (pos[NROWS - 1] == 0);
    const float CLOG = 13.287712379549449f / 32.0f;  // log2(10000)/32
    float invf0 = exp2f(-(float)(l15)      * CLOG);
    float invf1 = exp2f(-(float)(l15 + 16) * CLOG);
    int h = (cb + wn) >> 6;  // wave covers exactly one head (64 cols)
#pragma unroll
    for (int ni = 0; ni < 2; ++ni) {
      int col1 = cb + wn + ni*16 + l15;
      int d = ni*16 + l15;          // d in [0,32)
      float invf = (ni == 0) ? invf0 : invf1;
      float b1 = bias[col1];
      float b2 = bias[col1 + 32];
#pragma unroll
      for (int mi = 0; mi < 4; ++mi) {
#pragma unroll
        for (int r = 0; r < 4; ++r) {
          int row = rb + wm + mi*16 + q4*4 + r;
          int b = row >> 11, t = row & 2047;
          int pv = is64 ? pos[2*row] : pos[row];
          float ang = (float)pv * invf;
          float sn, cs;
          __sincosf(ang, &sn, &cs);
          float q1 = acc[mi][ni][r]   + b1;
          float q2 = acc[mi][ni+2][r] + b2;
          size_t base = (size_t)((b*N_HEADS + h)*SEQ + t)*HEAD_D;
          out[base + d]      = __float2bfloat16((q1*cs - q2*sn) * SCALE_Q);
          out[base + d + 32] = __float2bfloat16((q2*cs + q1*sn) * SCALE_Q);
        }
      }
    }
  }
}

// -------------------------------------------------------------------------
// Flash attention, S^T formulation + LDS-staged K/VT. (round-3 exact, the
// verified 125.5us version.)
// grid = 1024 blocks 1D, XCD-swizzled. block 256 (4 waves x 32 q-rows).
// Q pre-scaled by SCALE_Q (base-2 softmax).
// LDS (48KB): sK 16KB @0; sVT 16KB @16K; P: waves 0-1 alias sK (dead after
// QK barrier), waves 2-3 at [32K,48K). 3 barriers/iter.
// __launch_bounds__(256,2) is MANDATORY: (256,3) spills (round 2).
// NO live-register staging across the MFMA regions: round 4 proved even
// +32 VGPRs (T14 reg-staging) re-triggers the spill (WRITE 16->246MB,
// 125->202us). Pipelining here must be LDS/DMA-side, zero registers.
// -------------------------------------------------------------------------
__global__ __launch_bounds__(256, 2)
void attn_kernel(const bf16* __restrict__ Q, const bf16* __restrict__ K,
                 const bf16* __restrict__ VT, bf16* __restrict__ O) {
  __shared__ __align__(16) char smem[49152];
  char* sK  = smem;            // 128 rows x 128B, 16B chunks XOR-swizzled
  char* sVT = smem + 16384;    // 64 rows x 256B, 16B chunks XOR-swizzled

  const int tid  = threadIdx.x;
  const int lane = tid & 63, wid = tid >> 6;
  const int q4 = lane >> 4, l15 = lane & 15;
  const int n   = blockIdx.x;
  const int bh  = (n & 7) + 8 * (n >> 7);
  const int qb  = ((n >> 3) & 15) * 128;

  const bf16* Qp  = Q  + (size_t)bh * SEQ * HEAD_D;
  const bf16* Kp  = K  + (size_t)bh * SEQ * HEAD_D;
  const bf16* VTp = VT + (size_t)bh * HEAD_D * SEQ;
  // per-wave-private P^T: 32 rows(t) x 256B(m), swizzled. 8KB per wave.
  char* wP = smem + (wid & 1) * 8192 + (wid >> 1) * 32768;

  // resident Q fragments (B-operand): lane holds Q[t=l15(+16mi)][k=q4*8+j]
  bf16x8 qf[2][2];
#pragma unroll
  for (int mi = 0; mi < 2; ++mi)
#pragma unroll
    for (int kq = 0; kq < 2; ++kq) {
      int t = qb + wid*32 + mi*16 + l15;
      qf[mi][kq] = *(const bf16x8*)(Qp + (size_t)t*HEAD_D + kq*32 + q4*8);
    }

  const f32x4 z4 = {0.f, 0.f, 0.f, 0.f};
  f32x4 oacc[2][4];                 // O^T tiles: row=d (4q4+r), col=t (l15)
  float mrow[2], lrow[2];           // per-lane; t fixed per lane
#pragma unroll
  for (int mi = 0; mi < 2; ++mi) {
#pragma unroll
    for (int nd = 0; nd < 4; ++nd) oacc[mi][nd] = z4;
    mrow[mi] = -3.0e38f; lrow[mi] = 0.f;
  }

  for (int kv = 0; kv < 16; ++kv) {
    const int m0 = kv * 128;
    // stage K tile (128x64 elems): async, swizzled
#pragma unroll
    for (int i = 0; i < 4; ++i) {
      int o  = i*4096 + tid*16;
      int rr = o >> 7;
      int c0 = ((o >> 4) & 7) ^ (rr & 7);
      gload16(sK + i*4096 + (wid << 10),
              Kp + (size_t)(m0 + rr)*HEAD_D + c0*8);
    }
    // stage VT tile (64x128 elems): async, swizzled
#pragma unroll
    for (int i = 0; i < 4; ++i) {
      int o  = i*4096 + tid*16;
      int rr = o >> 8;
      int c0 = ((o >> 4) & 15) ^ (rr & 7);
      gload16(sVT + i*4096 + (wid << 10),
              VTp + (size_t)rr*SEQ + m0 + c0*8);
    }
    __syncthreads();   // staging complete

    // S^T = K·Q^T : st[mi][ni] row m = ni*16+4q4+r, col t = mi*16+l15
    f32x4 st[2][8];
#pragma unroll
    for (int mi = 0; mi < 2; ++mi)
#pragma unroll
      for (int ni = 0; ni < 8; ++ni) st[mi][ni] = z4;
#pragma unroll
    for (int kq = 0; kq < 2; ++kq) {
      const int cc = (kq*4 + q4) ^ (l15 & 7);
#pragma unroll
      for (int ni = 0; ni < 8; ++ni) {
        bf16x8 kf = *(const bf16x8*)(sK + (ni*16 + l15)*128 + cc*16);
        st[0][ni] = MFMA(kf, qf[0][kq], st[0][ni]);
        st[1][ni] = MFMA(kf, qf[1][kq], st[1][ni]);
      }
    }
    __syncthreads();   // all waves' sK reads done before P aliases it

    // online softmax over m; P^T -> wave-private LDS (no barrier needed)
#pragma unroll
    for (int mi = 0; mi < 2; ++mi) {
      float mloc = st[mi][0][0];
#pragma unroll
      for (int ni = 0; ni < 8; ++ni)
#pragma unroll
        for (int r = 0; r < 4; ++r) mloc = fmaxf(mloc, st[mi][ni][r]);
      mloc = fmaxf(mloc, __shfl_xor(mloc, 16, 64));
      mloc = fmaxf(mloc, __shfl_xor(mloc, 32, 64));
      float mn = fmaxf(mrow[mi], mloc);
      float al = EXP2(mrow[mi] - mn);
      mrow[mi] = mn;
      float rs = 0.f;
#pragma unroll
      for (int ni = 0; ni < 8; ++ni)
#pragma unroll
        for (int r = 0; r < 4; ++r) {
          float p = EXP2(st[mi][ni][r] - mn);
          st[mi][ni][r] = p;
          rs += p;
        }
      lrow[mi] = lrow[mi]*al + rs;
#pragma unroll
      for (int nd = 0; nd < 4; ++nd)
#pragma unroll
        for (int r = 0; r < 4; ++r) oacc[mi][nd][r] *= al;
      // pack 4 consecutive-m p's (in-lane) -> one b64 write per ni.
      // v_cvt_pk_bf16_f32: 1 instr/pair vs pkrne's 5.
      char* rowp = wP + (mi*16 + l15)*256;
#pragma unroll
      for (int ni = 0; ni < 8; ++ni) {
        uint2 pk;
        pk.x = cvtpk(st[mi][ni][0], st[mi][ni][1]);
        pk.y = cvtpk(st[mi][ni][2], st[mi][ni][3]);
        int c  = 2*ni + (q4 >> 1);
        int cs = c ^ (l15 & 7);
        *(uint2*)(rowp + cs*16 + 8*(q4 & 1)) = pk;
      }
    }

    // O^T += V^T · P^T  (A = V^T frag from sVT, B = P^T frag from own LDS)
#pragma unroll
    for (int kk = 0; kk < 4; ++kk) {
      const int cc = (kk*4 + q4) ^ (l15 & 7);
      bf16x8 vf[4];
#pragma unroll
      for (int nd = 0; nd < 4; ++nd)
        vf[nd] = *(const bf16x8*)(sVT + (nd*16 + l15)*256 + cc*16);
#pragma unroll
      for (int mi = 0; mi < 2; ++mi) {
        bf16x8 pb = *(const bf16x8*)(wP + (mi*16 + l15)*256 + cc*16);
#pragma unroll
        for (int nd = 0; nd < 4; ++nd)
          oacc[mi][nd] = MFMA(vf[nd], pb, oacc[mi][nd]);
      }
    }
    __syncthreads();   // PV reads done before next-iter staging overwrites
  }

  // epilogue: finish l across quads, O /= l, packed 8B stores
  const int b = bh >> 4, h = bh & 15;
#pragma unroll
  for (int mi = 0; mi < 2; ++mi) {
    float l = lrow[mi];
    l += __shfl_xor(l, 16, 64);
    l += __shfl_xor(l, 32, 64);
    float inv = 1.0f / l;
    int t = qb + wid*32 + mi*16 + l15;
#pragma unroll
    for (int nd = 0; nd < 4; ++nd) {
      uint2 pk;
      pk.x = pkrne(oacc[mi][nd][0]*inv, oacc[mi][nd][1]*inv);
      pk.y = pkrne(oacc[mi][nd][2]*inv, oacc[mi][nd][3]*inv);
      int d = nd*16 + 4*q4;
      *(uint2*)(O + (size_t)(b*SEQ + t)*D_MODEL + h*HEAD_D + d) = pk;
    }
  }
}

// -------------------------------------------------------------------------
extern "C" void kernel_launch(void* const* d_in, const int* in_sizes, int n_in,
                              void* d_out, int out_size, void* d_ws, size_t ws_size,
                              hipStream_t stream) {
  const float* query = (const float*)d_in[0];
  const float* key   = (const float*)d_in[1];
  const float* value = (const float*)d_in[2];
  const int*   pos   = (const int*)d_in[3];
  const float* Wq = (const float*)d_in[4];  const float* bq = (const float*)d_in[5];
  const float* Wk = (const float*)d_in[6];  const float* bk = (const float*)d_in[7];
  const float* Wv = (const float*)d_in[8];  const float* bv = (const float*)d_in[9];
  const float* Wo = (const float*)d_in[10]; const float* bo = (const float*)d_in[11];

  // ws layout (64 MB):
  //  [0,16M)  qbuf bf16 [b,h,t,d];  after attn: first 2MB = Wo bf16
  //  [16,32M) kbuf bf16 [b,h,m,d]
  //  [32,48M) vtbuf bf16 [b,h,d,m]
  //  [48,64M) obuf bf16 [b,t,h*64+d]; before attn: first 6MB = Wq/Wk/Wv bf16
  // d_out (32MB f32) doubles as bf16 activation scratch (16MB) until O-GEMM.
  char* ws = (char*)d_ws;
  bf16* qbuf  = (bf16*)(ws);
  bf16* kbuf  = (bf16*)(ws + (size_t)16777216);
  bf16* vtbuf = (bf16*)(ws + (size_t)33554432);
  bf16* obuf  = (bf16*)(ws + (size_t)50331648);
  bf16* wqb = obuf;                       // 1M bf16 = 2MB each, contiguous
  bf16* wkb = obuf + (size_t)1048576;
  bf16* wvb = obuf + (size_t)2097152;
  bf16* wob = qbuf;                       // written AFTER attn consumes qbuf
  bf16* xact = (bf16*)d_out;              // activation scratch in d_out

  dim3 blk(256);
  dim3 gproj(NROWS/128, D_MODEL/128);     // 64 x 8
  dim3 gprojT(D_MODEL/128, NROWS/128);    // 8 x 64 (flipped V)

  // Wq/Wk/Wv -> bf16 in one launch (2MB each, contiguous dst)
  convw3<<<1536, blk, 0, stream>>>(Wq, Wk, Wv, wqb);

  // V^T = (Wv X^T): A=wv bf16, B=value bf16 (converted into d_out scratch)
  convw<<<4096, blk, 0, stream>>>(value, xact);
  gemm_bt<2><<<gprojT, blk, 0, stream>>>(wvb, xact, bv, vtbuf, nullptr);

  convw<<<4096, blk, 0, stream>>>(key, xact);
  gemm_bt<1><<<gproj,  blk, 0, stream>>>(xact, wkb, bk, kbuf, nullptr);

  convw<<<4096, blk, 0, stream>>>(query, xact);
  gemm_bt<3><<<gproj,  blk, 0, stream>>>(xact, wqb, bq, qbuf, pos);

  attn_kernel<<<dim3(1024), blk, 0, stream>>>(qbuf, kbuf, vtbuf, obuf);

  // O-projection: A=obuf bf16, B=Wo bf16 (into qbuf, dead after attn), f32 out
  convw<<<512, blk, 0, stream>>>(Wo, wob);
  gemm_bt<0><<<gproj,  blk, 0, stream>>>(obuf, wob, bo, d_out, nullptr);
  (void)in_sizes; (void)n_in; (void)out_size; (void)ws_size;
}